// Round 1
// baseline (78.346 us; speedup 1.0000x reference)
//
#include <hip/hip_runtime.h>
#include <hip/hip_bf16.h>

#define NNODES 100000
#define NHE 20000
#define NEDGES 600000

typedef float f32x4 __attribute__((ext_vector_type(4)));
typedef short bf16x8 __attribute__((ext_vector_type(8)));
typedef short bf16x4 __attribute__((ext_vector_type(4)));

__device__ __forceinline__ unsigned short f2bf(float f) {
    unsigned u = __builtin_bit_cast(unsigned, f);
    u += 0x7fffu + ((u >> 16) & 1u);
    return (unsigned short)(u >> 16);
}

__global__ void k_init(int* last) {
    int i = blockIdx.x * 256 + threadIdx.x;
    if (i < NNODES) last[i] = -1;
}

__global__ void k_scatter(const int* __restrict__ sl, int* __restrict__ last) {
    int e = blockIdx.x * 256 + threadIdx.x;
    if (e < NEDGES) atomicMax(&last[sl[3 * e]], e);
}

// W_f (256x128 f32, row-major [k][c]) -> 4 chunk images of [c][kk] bf16,
// XOR-swizzled exactly as the main kernel's LDS wants them, so staging is a
// linear 16KB copy per chunk.
__global__ void k_prep_w(const float* __restrict__ Wf, unsigned short* __restrict__ wt) {
    int idx = blockIdx.x * 256 + threadIdx.x;  // 0..32767
    int k = idx >> 7, c = idx & 127;
    float v = Wf[idx];
    int chunk = k >> 6, kk = k & 63;
    int byte = (c * 128 + kk * 2) ^ ((c & 7) << 4);
    wt[chunk * 8192 + (byte >> 1)] = f2bf(v);
}

// C[100000][128] = [h_emb | node_emb] @ W_f, masked by has_edge.
// Tile: BM=128, N=128 full, K=256 in 4 chunks of 64. 256 threads = 4 waves (2x2),
// each wave 64x64 via 4x4 fragments of mfma_f32_16x16x32_bf16.
__global__ __launch_bounds__(256) void k_main(
    const float* __restrict__ node_emb,
    const float* __restrict__ he_emb,
    const int* __restrict__ sl,
    const int* __restrict__ last,
    const unsigned short* __restrict__ wt,
    float* __restrict__ out)
{
    __shared__ __align__(16) unsigned short Xs[128 * 64];  // 16KB, swizzled [row][kk]
    __shared__ __align__(16) unsigned short Ws[64 * 128];  // 16KB, swizzled [c][kk]
    __shared__ int he_s[128];
    __shared__ int valid_s[128];

    int t = threadIdx.x;
    int r0 = blockIdx.x * 128;

    if (t < 128) {
        int ri = r0 + t;
        int e = (ri < NNODES) ? last[ri] : -1;
        int v = (e >= 0) ? 1 : 0;
        he_s[t] = v ? sl[3 * e + 2] : 0;
        valid_s[t] = v;
    }
    __syncthreads();

    int lane = t & 63, w = t >> 6;
    int wm = w >> 1, wn = w & 1;
    int l15 = lane & 15, l4 = lane >> 4;

    f32x4 acc[4][4] = {};

    for (int kc = 0; kc < 4; ++kc) {
        // ---- stage X' chunk: 128 rows x 64 k, f32 -> bf16, swizzled ----
        #pragma unroll
        for (int i = 0; i < 8; ++i) {
            int idx = i * 256 + t;     // 0..2047 float4 slots
            int row = idx >> 4;        // 16 float4 per row
            int q = idx & 15;
            const float* src;
            if (kc < 2) {
                int hr = he_s[row];
                src = he_emb + hr * 128 + kc * 64 + q * 4;
            } else {
                int ri = r0 + row;
                if (ri >= NNODES) ri = NNODES - 1;
                src = node_emb + ri * 128 + (kc - 2) * 64 + q * 4;
            }
            f32x4 v = *(const f32x4*)src;
            bf16x4 p;
            p[0] = (short)f2bf(v[0]);
            p[1] = (short)f2bf(v[1]);
            p[2] = (short)f2bf(v[2]);
            p[3] = (short)f2bf(v[3]);
            int byte = (row * 128 + q * 8) ^ ((row & 7) << 4);
            *(bf16x4*)((char*)Xs + byte) = p;
        }
        // ---- stage W chunk: linear 16KB copy of pre-swizzled image ----
        {
            const f32x4* src = (const f32x4*)(wt + kc * 8192);
            f32x4* dst = (f32x4*)Ws;
            #pragma unroll
            for (int i = 0; i < 4; ++i) {
                int idx = i * 256 + t;  // 0..1023
                dst[idx] = src[idx];
            }
        }
        __syncthreads();

        // ---- compute: two K=32 steps ----
        #pragma unroll
        for (int ks = 0; ks < 2; ++ks) {
            bf16x8 af[4], bw[4];
            #pragma unroll
            for (int fm = 0; fm < 4; ++fm) {
                int row = wm * 64 + fm * 16 + l15;
                int byte = (row * 128 + ks * 64 + l4 * 16) ^ ((row & 7) << 4);
                af[fm] = *(const bf16x8*)((const char*)Xs + byte);
            }
            #pragma unroll
            for (int fn = 0; fn < 4; ++fn) {
                int rc = wn * 64 + fn * 16 + l15;
                int byte = (rc * 128 + ks * 64 + l4 * 16) ^ ((rc & 7) << 4);
                bw[fn] = *(const bf16x8*)((const char*)Ws + byte);
            }
            #pragma unroll
            for (int fm = 0; fm < 4; ++fm)
                #pragma unroll
                for (int fn = 0; fn < 4; ++fn)
                    acc[fm][fn] = __builtin_amdgcn_mfma_f32_16x16x32_bf16(
                        af[fm], bw[fn], acc[fm][fn], 0, 0, 0);
        }
        __syncthreads();
    }

    // ---- epilogue: D lane map col=lane&15, row=(lane>>4)*4+j ----
    #pragma unroll
    for (int fm = 0; fm < 4; ++fm) {
        #pragma unroll
        for (int j = 0; j < 4; ++j) {
            int lrow = wm * 64 + fm * 16 + l4 * 4 + j;
            int ri = r0 + lrow;
            if (ri < NNODES) {
                int v = valid_s[lrow];
                #pragma unroll
                for (int fn = 0; fn < 4; ++fn) {
                    int col = wn * 64 + fn * 16 + l15;
                    out[ri * 128 + col] = v ? acc[fm][fn][j] : 0.0f;
                }
            }
        }
    }
}

extern "C" void kernel_launch(void* const* d_in, const int* in_sizes, int n_in,
                              void* d_out, int out_size, void* d_ws, size_t ws_size,
                              hipStream_t stream) {
    const float* node_emb = (const float*)d_in[0];
    // d_in[1] = semalink_embeddings : dead code (softmax over size-1 axis -> gamma == 1)
    const float* he_emb = (const float*)d_in[2];
    const int* sl = (const int*)d_in[3];
    // d_in[4] = W_a : dead code
    const float* Wf = (const float*)d_in[5];
    float* out = (float*)d_out;

    int* last = (int*)d_ws;                                         // 400000 B
    unsigned short* wt = (unsigned short*)((char*)d_ws + 400128);   // 64 KB, 16B-aligned

    k_init<<<(NNODES + 255) / 256, 256, 0, stream>>>(last);
    k_scatter<<<(NEDGES + 255) / 256, 256, 0, stream>>>(sl, last);
    k_prep_w<<<128, 256, 0, stream>>>(Wf, wt);
    k_main<<<(NNODES + 127) / 128, 256, 0, stream>>>(node_emb, he_emb, sl, last, wt, out);
}